// Round 5
// baseline (290.877 us; speedup 1.0000x reference)
//
#include <hip/hip_runtime.h>
#include <stdint.h>

#define BH 32
#define LSEQ 4096
#define DDIM 128
#define CHUNKS 16
#define CHUNK_ROWS 256
#define STATE_SZ (DDIM*DDIM + DDIM)   // 16512 floats per (bh, chunk), [d][e] then Z[d]

typedef __attribute__((ext_vector_type(8))) short bf16x8;
typedef __attribute__((ext_vector_type(4))) float f32x4;

__device__ inline uint16_t f2bf(float f) {
    uint32_t x = __builtin_bit_cast(uint32_t, f);
    x += 0x7fffu + ((x >> 16) & 1u);
    return (uint16_t)(x >> 16);
}
__device__ inline uint32_t pack2(float a, float b) {
    return (uint32_t)f2bf(a) | ((uint32_t)f2bf(b) << 16);
}
// phi(x) = clip(elu(x*s+b)+1, 0, 10)
__device__ inline float phi_f(float x, float s, float b) {
    float y = fmaf(x, s, b);
    float pos = fminf(y + 1.0f, 10.0f);
    float neg = __expf(y);
    return (y > 0.0f) ? pos : neg;
}
// LDS-only barrier drain: keeps global prefetch loads in flight across barriers.
__device__ inline void bar_lgkm() {
    asm volatile("s_waitcnt lgkmcnt(0)\n\ts_barrier" ::: "memory");
}

// =====================================================================
// P1: per-chunk state totals  S_c = phi_K_c^T @ V_c  (K=256), Z_c
// LDS: pk bufs 2x16KB @0, vT bufs 2x16KB @32768, Zpart @65536 (2KB)
// NOTE: __launch_bounds__ second arg behaves as BLOCKS/CU here (measured:
// (512,4) capped VGPR at 64 and spilled; (512,2) gives the 128-reg budget).
#define SMEM1 67584
__global__ __launch_bounds__(512, 2) void la_state(
    const float* __restrict__ K, const float* __restrict__ V,
    const float* __restrict__ scale, const float* __restrict__ bias,
    float* __restrict__ states)
{
    extern __shared__ char smem[];
    const int tid  = threadIdx.x;
    const int bh   = blockIdx.x >> 4;
    const int ch   = blockIdx.x & 15;
    const int h    = bh & 15;
    const int lane = tid & 63;
    const int wid  = tid >> 6;
    const int i15  = lane & 15;
    const int q4   = lane >> 4;
    const size_t base = (size_t)bh * LSEQ * DDIM;
    const int row0 = ch * CHUNK_ROWS;

    const int d  = tid & 127;
    const int rg = tid >> 7;
    const float sk = scale[h*DDIM + d];
    const float bk = bias [h*DDIM + d];

    f32x4 accS[8];
    #pragma unroll
    for (int mt = 0; mt < 8; ++mt) accS[mt] = (f32x4){0.f,0.f,0.f,0.f};
    float zacc = 0.f;

    float kreg[16], vreg[16];
    auto load_kv = [&](int g) {
        const float* Kc = K + base + (size_t)(row0 + 64*g + 16*rg)*DDIM + d;
        const float* Vc = V + base + (size_t)(row0 + 64*g + 16*rg)*DDIM + d;
        #pragma unroll
        for (int j = 0; j < 16; ++j) {
            kreg[j] = Kc[(size_t)j*DDIM];
            vreg[j] = Vc[(size_t)j*DDIM];
        }
    };
    auto stage = [&](int b) {
        uint32_t wk[8], wv8[8];
        #pragma unroll
        for (int j = 0; j < 8; ++j) {
            float p0 = phi_f(kreg[2*j],   sk, bk);
            float p1 = phi_f(kreg[2*j+1], sk, bk);
            zacc += p0 + p1;
            wk[j]  = pack2(p0, p1);
            wv8[j] = pack2(vreg[2*j], vreg[2*j+1]);
        }
        char* pkb = smem + b*16384;
        char* vtb = smem + 32768 + b*16384;
        const uint32_t lin = (uint32_t)(d*128 + 32*rg);
        const uint32_t swz = (uint32_t)((d & 7) << 4);
        *(uint4*)(pkb + ((lin     ) ^ swz)) = ((const uint4*)wk)[0];
        *(uint4*)(pkb + ((lin + 16) ^ swz)) = ((const uint4*)wk)[1];
        *(uint4*)(vtb + ((lin     ) ^ swz)) = ((const uint4*)wv8)[0];
        *(uint4*)(vtb + ((lin + 16) ^ swz)) = ((const uint4*)wv8)[1];
    };

    load_kv(0);
    stage(0);
    load_kv(1);
    bar_lgkm();

    #pragma unroll
    for (int g = 0; g < 4; ++g) {
        if (g < 3) stage((g+1)&1);
        if (g < 2) load_kv(g+2);
        const char* pkb = smem + (g&1)*16384;
        const char* vtb = smem + 32768 + (g&1)*16384;
        const uint32_t swz = (uint32_t)((i15 & 7) << 4);
        #pragma unroll
        for (int ksl = 0; ksl < 2; ++ksl) {
            bf16x8 bv = *(const bf16x8*)(vtb + (((uint32_t)((16*wid+i15)*128 + 64*ksl + 16*q4)) ^ swz));
            #pragma unroll
            for (int mt = 0; mt < 8; ++mt) {
                bf16x8 av = *(const bf16x8*)(pkb + (((uint32_t)((16*mt+i15)*128 + 64*ksl + 16*q4)) ^ swz));
                accS[mt] = __builtin_amdgcn_mfma_f32_16x16x32_bf16(av, bv, accS[mt], 0, 0, 0);
            }
        }
        bar_lgkm();
    }

    float* Zpart = (float*)(smem + 65536);
    Zpart[rg*128 + d] = zacc;
    float* stb = states + (size_t)(bh*CHUNKS + ch)*STATE_SZ;
    #pragma unroll
    for (int mt = 0; mt < 8; ++mt)
        #pragma unroll
        for (int r = 0; r < 4; ++r)
            stb[(size_t)(16*mt + 4*q4 + r)*DDIM + 16*wid + i15] = accS[mt][r];
    bar_lgkm();
    if (tid < 128)
        stb[DDIM*DDIM + tid] = Zpart[tid] + Zpart[128+tid] + Zpart[256+tid] + Zpart[384+tid];
}

// =====================================================================
// Prefix: in-place exclusive prefix over the 16 chunk states, 1 chain/thread.
__global__ void la_prefix(float* __restrict__ states) {
    const int bh  = blockIdx.y;
    const int idx = blockIdx.x * 128 + threadIdx.x;   // 129*128 = 16512 exact
    float* p = states + (size_t)bh * CHUNKS * STATE_SZ + idx;
    float run = 0.f;
    #pragma unroll
    for (int c = 0; c < CHUNKS; ++c) {
        float v = p[(size_t)c * STATE_SZ];
        p[(size_t)c * STATE_SZ] = run;
        run += v;
    }
}

// =====================================================================
// P2: out = (phi_Q @ S0 + blockcausal(phi_Q @ phi_K^T) @ V) / den
// HALF-CHUNK per wg (128 q-rows): wave w owns ONE 16-row q-tile (global tile
// a = 8*half + w). acc = 32 AGPRs, pq = 16 VGPRs -> total regs ~110 incl
// AGPRs -> 2 wg/CU (the R2/R4 blocker was arch+AGPR > 128 -> 1 wg/CU).
// Grid 1024; blockIdx remapped so both halves of a chunk land on the same
// XCD (shared K/V granules + S0 hit that XCD's L2).
// LDS map (71168 B):
//   [0,32768)       S0T [e=128][d=128] bf16 swz; A-scratch overlays after
//                   term1 (per wave: wid*1280, [16 q][40 r] bf16)
//   [32768,49152)   pk bufs 2 x [32 r][128 d] bf16 swz (8KB each)
//   [49152,69632)   vT bufs 2 x [128 e][40 r] bf16 pad (10KB each)
//   [69632,70656)   sbL: scale[128], bias[128] f32
//   [70656,71168)   denl [8 waves][16] f32
#define SMEM2 71168
__global__ __launch_bounds__(512, 2) void la_fwd(
    const float* __restrict__ Q, const float* __restrict__ K,
    const float* __restrict__ V, const float* __restrict__ scale,
    const float* __restrict__ bias, const float* __restrict__ states,
    float* __restrict__ out)
{
    extern __shared__ char smem[];
    char* S0T  = smem;
    char* pkB  = smem + 32768;
    char* vtB  = smem + 49152;
    float* sbL  = (float*)(smem + 69632);
    float* denl = (float*)(smem + 70656);

    const int tid  = threadIdx.x;
    const int b    = blockIdx.x;
    // XCD-contiguous bijective remap (1024 = 8 XCD * 128): halves of a chunk
    // get adjacent lids -> same XCD under round-robin dispatch.
    const int lid  = ((b & 7) << 7) | (b >> 3);
    const int half = lid & 1;
    const int cgid = lid >> 1;
    const int bh   = cgid >> 4;
    const int ch   = cgid & 15;
    const int h    = bh & 15;
    const int lane = tid & 63;
    const int wid  = tid >> 6;
    const int i15  = lane & 15;
    const int q4   = lane >> 4;
    const size_t base = (size_t)bh * LSEQ * DDIM;
    const int row0  = ch * CHUNK_ROWS;
    const int qrow0 = row0 + half*128;
    const int NG    = 4 + 4*half;         // kv granules (32 rows each) needed
    const int jm    = 4*half + (wid >> 1);// last granule for this wave's tile
    const float* stb = states + (size_t)(bh*CHUNKS + ch)*STATE_SZ;

    // kv staging assignments (32-row granule)
    const int krow = tid >> 4;            // 0..31
    const int kc8  = (tid & 15) * 8;      // K col segment (8 wide)
    const int ve   = tid & 127;           // vT row (e)
    const int vrg  = tid >> 7;            // 0..3 -> r rows 8vrg..8vrg+7

    float4 kq[2];
    float  vr[8];
    auto load_kv = [&](int g) {
        const float* Kr = K + base + (size_t)(row0 + 32*g + krow)*DDIM + kc8;
        kq[0] = *(const float4*)(Kr);
        kq[1] = *(const float4*)(Kr + 4);
        const float* Vc = V + base + (size_t)(row0 + 32*g + 8*vrg)*DDIM + ve;
        #pragma unroll
        for (int j = 0; j < 8; ++j) vr[j] = Vc[(size_t)j*DDIM];
    };
    auto stage_kv = [&](int bb) {
        float4 s0 = *(const float4*)&sbL[kc8];
        float4 s1 = *(const float4*)&sbL[kc8 + 4];
        float4 b0 = *(const float4*)&sbL[128 + kc8];
        float4 b1 = *(const float4*)&sbL[128 + kc8 + 4];
        uint32_t wk[4];
        wk[0] = pack2(phi_f(kq[0].x, s0.x, b0.x), phi_f(kq[0].y, s0.y, b0.y));
        wk[1] = pack2(phi_f(kq[0].z, s0.z, b0.z), phi_f(kq[0].w, s0.w, b0.w));
        wk[2] = pack2(phi_f(kq[1].x, s1.x, b1.x), phi_f(kq[1].y, s1.y, b1.y));
        wk[3] = pack2(phi_f(kq[1].z, s1.z, b1.z), phi_f(kq[1].w, s1.w, b1.w));
        const uint32_t lin = (uint32_t)(krow*256 + kc8*2);
        const uint32_t swz = (uint32_t)((krow & 7) << 4);
        *(uint4*)(pkB + bb*8192 + (lin ^ swz)) = *(const uint4*)wk;
        uint32_t wv8[4];
        #pragma unroll
        for (int j = 0; j < 4; ++j) wv8[j] = pack2(vr[2*j], vr[2*j+1]);
        *(uint4*)(vtB + bb*10240 + (uint32_t)(ve*80 + vrg*16)) = *(const uint4*)wv8;
    };

    load_kv(0);   // issue earliest

    // ---- stage scale/bias row into LDS
    if (tid < 256) sbL[tid] = (tid < 128) ? scale[h*DDIM + tid] : bias[h*DDIM + tid - 128];

    // ---- stage S0T [e][d] bf16 (2 passes of 16 d's to cap registers)
    {
        const int se  = tid & 127;
        const int sdg = tid >> 7;            // d range 32sdg..32sdg+31
        const uint32_t swz = (uint32_t)((se & 7) << 4);
        #pragma unroll
        for (int pass = 0; pass < 2; ++pass) {
            float sv[16];
            const float* sp = stb + (size_t)(32*sdg + 16*pass)*DDIM + se;
            #pragma unroll
            for (int k2 = 0; k2 < 16; ++k2) sv[k2] = sp[(size_t)k2*DDIM];
            uint32_t wbuf[8];
            #pragma unroll
            for (int k2 = 0; k2 < 8; ++k2) wbuf[k2] = pack2(sv[2*k2], sv[2*k2+1]);
            const uint32_t linb = (uint32_t)(se*256 + (32*sdg + 16*pass)*2);
            *(uint4*)(S0T + ((linb     ) ^ swz)) = ((const uint4*)wbuf)[0];
            *(uint4*)(S0T + ((linb + 16) ^ swz)) = ((const uint4*)wbuf)[1];
        }
    }

    // ---- phi_Q fragments (single tile) + den0 = phi_q . Z0
    bf16x8 pq[4];
    float dden = 0.f;
    #pragma unroll
    for (int ks = 0; ks < 4; ++ks) {
        const float* sp = scale + h*DDIM + 32*ks + 8*q4;
        const float* bp = bias  + h*DDIM + 32*ks + 8*q4;
        const float* zp = stb + DDIM*DDIM + 32*ks + 8*q4;
        float4 s0 = *(const float4*)sp, s1 = *(const float4*)(sp+4);
        float4 b0 = *(const float4*)bp, b1 = *(const float4*)(bp+4);
        float4 z0 = *(const float4*)zp, z1 = *(const float4*)(zp+4);
        const float* qp = Q + base + (size_t)(qrow0 + 16*wid + i15)*DDIM + 32*ks + 8*q4;
        float4 a0 = *(const float4*)qp, a1 = *(const float4*)(qp+4);
        float f0 = phi_f(a0.x, s0.x, b0.x), f1 = phi_f(a0.y, s0.y, b0.y);
        float f2 = phi_f(a0.z, s0.z, b0.z), f3 = phi_f(a0.w, s0.w, b0.w);
        float f4 = phi_f(a1.x, s1.x, b1.x), f5 = phi_f(a1.y, s1.y, b1.y);
        float f6 = phi_f(a1.z, s1.z, b1.z), f7 = phi_f(a1.w, s1.w, b1.w);
        dden += f0*z0.x + f1*z0.y + f2*z0.z + f3*z0.w
              + f4*z1.x + f5*z1.y + f6*z1.z + f7*z1.w;
        uint4 uu = { pack2(f0,f1), pack2(f2,f3), pack2(f4,f5), pack2(f6,f7) };
        pq[ks] = __builtin_bit_cast(bf16x8, uu);
    }

    stage_kv(0);
    load_kv(1);
    bar_lgkm();   // B0: S0T + sbL + kv g0 visible

    // ---- term1: acc = phi_q @ S0
    f32x4 acc[8];
    #pragma unroll
    for (int et = 0; et < 8; ++et) acc[et] = (f32x4){0.f,0.f,0.f,0.f};
    {
        const uint32_t swz = (uint32_t)((i15 & 7) << 4);
        #pragma unroll
        for (int ks = 0; ks < 4; ++ks)
            #pragma unroll
            for (int et = 0; et < 8; ++et) {
                bf16x8 sb = *(const bf16x8*)(S0T + (((uint32_t)((16*et+i15)*256 + (32*ks + 8*q4)*2)) ^ swz));
                acc[et] = __builtin_amdgcn_mfma_f32_16x16x32_bf16(pq[ks], sb, acc[et], 0, 0, 0);
            }
    }
    stage_kv(1);
    if (NG > 2) load_kv(2);
    bar_lgkm();   // B1: term1 S0T reads done -> A-scratch may overwrite; kv g1 visible

    // ---- kv loop: NG granules of 32 rows (granule t == kv block t), dbuf
    char* Ascr = S0T + wid*1280;
    const uint32_t swzf = (uint32_t)((i15 & 7) << 4);

    for (int t = 0; t < NG; ++t) {
        if (t >= 1) {
            if (t + 1 < NG) stage_kv((t+1)&1);
            if (t + 2 < NG) load_kv(t+2);
        }
        const char* pk = pkB + (t&1)*8192;
        const char* vt = vtB + (t&1)*10240;
        if (t <= jm) {
            f32x4 Aacc[2];
            Aacc[0] = (f32x4){0.f,0.f,0.f,0.f};
            Aacc[1] = (f32x4){0.f,0.f,0.f,0.f};
            #pragma unroll
            for (int ks = 0; ks < 4; ++ks) {
                bf16x8 ak0 = *(const bf16x8*)(pk + (((uint32_t)((     i15)*256 + (32*ks + 8*q4)*2)) ^ swzf));
                bf16x8 ak1 = *(const bf16x8*)(pk + (((uint32_t)((16 + i15)*256 + (32*ks + 8*q4)*2)) ^ swzf));
                Aacc[0] = __builtin_amdgcn_mfma_f32_16x16x32_bf16(ak0, pq[ks], Aacc[0], 0, 0, 0);
                Aacc[1] = __builtin_amdgcn_mfma_f32_16x16x32_bf16(ak1, pq[ks], Aacc[1], 0, 0, 0);
            }
            dden += Aacc[0][0]+Aacc[0][1]+Aacc[0][2]+Aacc[0][3]
                  + Aacc[1][0]+Aacc[1][1]+Aacc[1][2]+Aacc[1][3];
            #pragma unroll
            for (int sub = 0; sub < 2; ++sub) {
                uint2 o;
                o.x = pack2(Aacc[sub][0], Aacc[sub][1]);
                o.y = pack2(Aacc[sub][2], Aacc[sub][3]);
                *(uint2*)(Ascr + (uint32_t)((i15*40 + 16*sub + 4*q4)*2)) = o;
            }
            bf16x8 aq = *(const bf16x8*)(Ascr + (uint32_t)((i15*40 + 8*q4)*2));
            #pragma unroll
            for (int et = 0; et < 8; ++et) {
                bf16x8 bv = *(const bf16x8*)(vt + (uint32_t)((16*et+i15)*80 + q4*16));
                acc[et] = __builtin_amdgcn_mfma_f32_16x16x32_bf16(aq, bv, acc[et], 0, 0, 0);
            }
        }
        bar_lgkm();
    }

    // ---- den reduce (wave-private) + normalize + store
    dden += __shfl_xor(dden, 16, 64);
    dden += __shfl_xor(dden, 32, 64);
    if (q4 == 0) denl[wid*16 + i15] = dden;
    float inv[4];
    #pragma unroll
    for (int r = 0; r < 4; ++r)
        inv[r] = 1.0f / fmaxf(denl[wid*16 + 4*q4 + r], 1e-6f);
    #pragma unroll
    for (int et = 0; et < 8; ++et)
        #pragma unroll
        for (int r = 0; r < 4; ++r)
            out[base + (size_t)(qrow0 + 16*wid + 4*q4 + r)*DDIM + 16*et + i15] =
                acc[et][r] * inv[r];
}

extern "C" void kernel_launch(void* const* d_in, const int* in_sizes, int n_in,
                              void* d_out, int out_size, void* d_ws, size_t ws_size,
                              hipStream_t stream) {
    const float* Q     = (const float*)d_in[0];
    const float* K     = (const float*)d_in[1];
    const float* V     = (const float*)d_in[2];
    const float* scale = (const float*)d_in[3];
    const float* bias  = (const float*)d_in[4];
    float* out    = (float*)d_out;
    float* states = (float*)d_ws;   // 32*16*16512*4 = 33.8 MB

    static bool s_attr = false;
    if (!s_attr) {
        hipFuncSetAttribute(reinterpret_cast<const void*>(la_state),
                            hipFuncAttributeMaxDynamicSharedMemorySize, SMEM1);
        hipFuncSetAttribute(reinterpret_cast<const void*>(la_fwd),
                            hipFuncAttributeMaxDynamicSharedMemorySize, SMEM2);
        s_attr = true;
    }

    hipLaunchKernelGGL(la_state, dim3(BH*CHUNKS), dim3(512), SMEM1, stream,
                       K, V, scale, bias, states);
    hipLaunchKernelGGL(la_prefix, dim3(129, BH), dim3(128), 0, stream, states);
    hipLaunchKernelGGL(la_fwd, dim3(BH*CHUNKS*2), dim3(512), SMEM2, stream,
                       Q, K, V, scale, bias, states, out);
}

// Round 7
// 278.668 us; speedup vs baseline: 1.0438x; 1.0438x over previous
//
#include <hip/hip_runtime.h>
#include <stdint.h>

#define BH 32
#define LSEQ 4096
#define DDIM 128
#define CHUNKS 16
#define CHUNK_ROWS 256
#define STATE_SZ (DDIM*DDIM + DDIM)   // 16512 floats per (bh, chunk), [d][e] then Z[d]

typedef __attribute__((ext_vector_type(8))) short bf16x8;
typedef __attribute__((ext_vector_type(4))) float f32x4;

__device__ inline uint16_t f2bf(float f) {
    uint32_t x = __builtin_bit_cast(uint32_t, f);
    x += 0x7fffu + ((x >> 16) & 1u);
    return (uint16_t)(x >> 16);
}
__device__ inline uint32_t pack2(float a, float b) {
    return (uint32_t)f2bf(a) | ((uint32_t)f2bf(b) << 16);
}
// phi(x) = clip(elu(x*s+b)+1, 0, 10)
__device__ inline float phi_f(float x, float s, float b) {
    float y = fmaf(x, s, b);
    float pos = fminf(y + 1.0f, 10.0f);
    float neg = __expf(y);
    return (y > 0.0f) ? pos : neg;
}
// LDS-only barrier drain: keeps global prefetch loads in flight across barriers.
__device__ inline void bar_lgkm() {
    asm volatile("s_waitcnt lgkmcnt(0)\n\ts_barrier" ::: "memory");
}

// =====================================================================
// P1: per-chunk state totals  S_c = phi_K_c^T @ V_c  (K=256), Z_c
// 32-row granules, double-buffered. LDS 34816 B -> 3 wg/CU target.
//   [0,16384)      pk bufs 2 x [128 d][32 r] bf16, 64B rows, swz (d&7)<<4
//   [16384,32768)  vT bufs 2 x [128 e][32 r] bf16, same swz
//   [32768,34816)  Zpart [4][128] f32
#define SMEM1 34816
__global__ __launch_bounds__(512, 3) void la_state(
    const float* __restrict__ K, const float* __restrict__ V,
    const float* __restrict__ scale, const float* __restrict__ bias,
    float* __restrict__ states)
{
    extern __shared__ char smem[];
    const int tid  = threadIdx.x;
    const int bh   = blockIdx.x >> 4;
    const int ch   = blockIdx.x & 15;
    const int h    = bh & 15;
    const int lane = tid & 63;
    const int wid  = tid >> 6;
    const int i15  = lane & 15;
    const int q4   = lane >> 4;
    const size_t base = (size_t)bh * LSEQ * DDIM;
    const int row0 = ch * CHUNK_ROWS;

    const int d  = tid & 127;
    const int rg = tid >> 7;              // 0..3 -> rows 8rg..8rg+7 of a 32-row granule
    const float sk = scale[h*DDIM + d];
    const float bk = bias [h*DDIM + d];

    f32x4 accS[8];
    #pragma unroll
    for (int mt = 0; mt < 8; ++mt) accS[mt] = (f32x4){0.f,0.f,0.f,0.f};
    float zacc = 0.f;

    float kreg[8], vreg[8];
    auto load_kv = [&](int g) {
        const float* Kc = K + base + (size_t)(row0 + 32*g + 8*rg)*DDIM + d;
        const float* Vc = V + base + (size_t)(row0 + 32*g + 8*rg)*DDIM + d;
        #pragma unroll
        for (int j = 0; j < 8; ++j) {
            kreg[j] = Kc[(size_t)j*DDIM];
            vreg[j] = Vc[(size_t)j*DDIM];
        }
    };
    auto stage = [&](int b) {   // current regs -> buf b, transposed [col][r]
        uint32_t wk[4], wv[4];
        #pragma unroll
        for (int j = 0; j < 4; ++j) {
            float p0 = phi_f(kreg[2*j],   sk, bk);
            float p1 = phi_f(kreg[2*j+1], sk, bk);
            zacc += p0 + p1;
            wk[j] = pack2(p0, p1);
            wv[j] = pack2(vreg[2*j], vreg[2*j+1]);
        }
        const uint32_t off = ((uint32_t)(d*64 + rg*16)) ^ ((uint32_t)((d&7)<<4));
        *(uint4*)(smem + b*8192 + off)         = *(const uint4*)wk;
        *(uint4*)(smem + 16384 + b*8192 + off) = *(const uint4*)wv;
    };

    load_kv(0);
    stage(0);
    load_kv(1);
    bar_lgkm();

    for (int g = 0; g < 8; ++g) {
        if (g + 1 < 8) stage((g+1)&1);
        if (g + 2 < 8) load_kv(g+2);
        const char* pkb = smem + (g&1)*8192;
        const char* vtb = smem + 16384 + (g&1)*8192;
        const uint32_t swz = (uint32_t)((i15&7)<<4);
        bf16x8 bv = *(const bf16x8*)(vtb + (((uint32_t)((16*wid+i15)*64 + q4*16)) ^ swz));
        #pragma unroll
        for (int mt = 0; mt < 8; ++mt) {
            bf16x8 av = *(const bf16x8*)(pkb + (((uint32_t)((16*mt+i15)*64 + q4*16)) ^ swz));
            accS[mt] = __builtin_amdgcn_mfma_f32_16x16x32_bf16(av, bv, accS[mt], 0, 0, 0);
        }
        bar_lgkm();
    }

    float* Zpart = (float*)(smem + 32768);
    Zpart[rg*128 + d] = zacc;
    float* stb = states + (size_t)(bh*CHUNKS + ch)*STATE_SZ;
    #pragma unroll
    for (int mt = 0; mt < 8; ++mt)
        #pragma unroll
        for (int r = 0; r < 4; ++r)
            stb[(size_t)(16*mt + 4*q4 + r)*DDIM + 16*wid + i15] = accS[mt][r];
    bar_lgkm();
    if (tid < 128)
        stb[DDIM*DDIM + tid] = Zpart[tid] + Zpart[128+tid] + Zpart[256+tid] + Zpart[384+tid];
}

// =====================================================================
// Prefix: in-place exclusive prefix over the 16 chunk states, float4 chains.
__global__ void la_prefix(float* __restrict__ states) {
    const int bh  = blockIdx.y;
    const int idx = blockIdx.x * 128 + threadIdx.x;
    if (idx >= STATE_SZ/4) return;            // 4128 float4 chains per bh
    float4* p = (float4*)(states + (size_t)bh * CHUNKS * STATE_SZ) + idx;
    float4 run = {0.f, 0.f, 0.f, 0.f};
    #pragma unroll
    for (int c = 0; c < CHUNKS; ++c) {
        float4 v = p[(size_t)c * (STATE_SZ/4)];
        p[(size_t)c * (STATE_SZ/4)] = run;
        run.x += v.x; run.y += v.y; run.z += v.z; run.w += v.w;
    }
}

// =====================================================================
// P2: out = (phi_Q @ S0 + blockcausal(phi_Q @ phi_K^T) @ V) / den
// Wave w owns q-tiles a=w and a=15-w (balanced). kv granules of 32 rows, dbuf.
// LDS 55296 B (<=57984 proven 2 wg/CU):
//   [0,16384)      S0 quarter bufs 2 x [32 e][128 d] bf16 (256B rows, swz
//                  (e&7)<<4); quarter qt lives in buf qt&1. After B4 ->
//                  Ascr per wave (wid*1280, [16][40] bf16)
//   [16384,32768)  pk bufs 2 x [32 r][128 d] bf16 swz (8KB each)
//   [32768,53248)  vT bufs 2 x [128 e][40 r] bf16 pad (10KB each)
//   [53248,54272)  sbL: scale[128], bias[128] f32
//   [54272,55296)  denl [8 waves][32] f32
#define SMEM2 55296
__global__ __launch_bounds__(512, 2) void la_fwd(
    const float* __restrict__ Q, const float* __restrict__ K,
    const float* __restrict__ V, const float* __restrict__ scale,
    const float* __restrict__ bias, const float* __restrict__ states,
    float* __restrict__ out)
{
    extern __shared__ char smem[];
    char* S0q  = smem;
    char* pkB  = smem + 16384;
    char* vtB  = smem + 32768;
    float* sbL  = (float*)(smem + 53248);
    float* denl = (float*)(smem + 54272);

    const int tid  = threadIdx.x;
    const int bh   = blockIdx.x >> 4;
    const int ch   = blockIdx.x & 15;
    const int h    = bh & 15;
    const int lane = tid & 63;
    const int wid  = tid >> 6;
    const int i15  = lane & 15;
    const int q4   = lane >> 4;
    const size_t base = (size_t)bh * LSEQ * DDIM;
    const int row0 = ch * CHUNK_ROWS;
    const float* stb = states + (size_t)(bh*CHUNKS + ch)*STATE_SZ;

    // kv staging (32-row granule)
    const int krow = tid >> 4;            // 0..31
    const int kc8  = (tid & 15) * 8;      // K col segment
    const int ve   = tid & 127;           // vT row (e)
    const int vrg  = tid >> 7;            // r rows 8vrg..8vrg+7
    // S0 quarter staging
    const int se32  = tid & 31;           // e within quarter
    const int sdg32 = tid >> 5;           // 0..15 -> d 8sdg..8sdg+7

    // balanced q-tile ownership
    const int qa0 = wid, qa1 = 15 - wid;
    const int jm0 = qa0 >> 1, jm1 = qa1 >> 1;

    float4 kq[2];
    float  vr[8];
    auto load_kv = [&](int g) {
        const float* Kr = K + base + (size_t)(row0 + 32*g + krow)*DDIM + kc8;
        kq[0] = *(const float4*)(Kr);
        kq[1] = *(const float4*)(Kr + 4);
        const float* Vc = V + base + (size_t)(row0 + 32*g + 8*vrg)*DDIM + ve;
        #pragma unroll
        for (int j = 0; j < 8; ++j) vr[j] = Vc[(size_t)j*DDIM];
    };
    auto stage_kv = [&](int bb) {   // reads sbL -> only call after B0
        float4 s0 = *(const float4*)&sbL[kc8];
        float4 s1 = *(const float4*)&sbL[kc8 + 4];
        float4 b0 = *(const float4*)&sbL[128 + kc8];
        float4 b1 = *(const float4*)&sbL[128 + kc8 + 4];
        uint32_t wk[4];
        wk[0] = pack2(phi_f(kq[0].x, s0.x, b0.x), phi_f(kq[0].y, s0.y, b0.y));
        wk[1] = pack2(phi_f(kq[0].z, s0.z, b0.z), phi_f(kq[0].w, s0.w, b0.w));
        wk[2] = pack2(phi_f(kq[1].x, s1.x, b1.x), phi_f(kq[1].y, s1.y, b1.y));
        wk[3] = pack2(phi_f(kq[1].z, s1.z, b1.z), phi_f(kq[1].w, s1.w, b1.w));
        const uint32_t lin = (uint32_t)(krow*256 + kc8*2);
        const uint32_t swz = (uint32_t)((krow & 7) << 4);
        *(uint4*)(pkB + bb*8192 + (lin ^ swz)) = *(const uint4*)wk;
        uint32_t wv[4];
        #pragma unroll
        for (int j = 0; j < 4; ++j) wv[j] = pack2(vr[2*j], vr[2*j+1]);
        *(uint4*)(vtB + bb*10240 + (uint32_t)(ve*80 + vrg*16)) = *(const uint4*)wv;
    };

    float sv[8];
    auto s0_load = [&](int qt) {
        const float* sp = stb + (size_t)(8*sdg32)*DDIM + 32*qt + se32;
        #pragma unroll
        for (int j = 0; j < 8; ++j) sv[j] = sp[(size_t)j*DDIM];
    };
    auto s0_write = [&](int qt) {    // quarter qt -> buf (qt&1)  [R6 bug: used qt directly]
        uint32_t w[4];
        #pragma unroll
        for (int j = 0; j < 4; ++j) w[j] = pack2(sv[2*j], sv[2*j+1]);
        const uint32_t lin = (uint32_t)(se32*256 + sdg32*16);
        const uint32_t swz = (uint32_t)((se32 & 7) << 4);
        *(uint4*)(S0q + (qt&1)*8192 + (lin ^ swz)) = *(const uint4*)w;
    };

    load_kv(0);
    if (tid < 256) sbL[tid] = (tid < 128) ? scale[h*DDIM + tid] : bias[h*DDIM + tid - 128];
    s0_load(0);

    // ---- phi_Q fragments + den0 = phi_q . Z0
    bf16x8 pq[2][4];
    float dden0 = 0.f, dden1 = 0.f;
    #pragma unroll
    for (int ks = 0; ks < 4; ++ks) {
        const float* sp = scale + h*DDIM + 32*ks + 8*q4;
        const float* bp = bias  + h*DDIM + 32*ks + 8*q4;
        const float* zp = stb + DDIM*DDIM + 32*ks + 8*q4;
        float4 s0 = *(const float4*)sp, s1 = *(const float4*)(sp+4);
        float4 b0 = *(const float4*)bp, b1 = *(const float4*)(bp+4);
        float4 z0 = *(const float4*)zp, z1 = *(const float4*)(zp+4);
        #pragma unroll
        for (int tl = 0; tl < 2; ++tl) {
            const int a = tl ? qa1 : qa0;
            const float* qp = Q + base + (size_t)(row0 + 16*a + i15)*DDIM + 32*ks + 8*q4;
            float4 a0 = *(const float4*)qp, a1 = *(const float4*)(qp+4);
            float f0 = phi_f(a0.x, s0.x, b0.x), f1 = phi_f(a0.y, s0.y, b0.y);
            float f2 = phi_f(a0.z, s0.z, b0.z), f3 = phi_f(a0.w, s0.w, b0.w);
            float f4 = phi_f(a1.x, s1.x, b1.x), f5 = phi_f(a1.y, s1.y, b1.y);
            float f6 = phi_f(a1.z, s1.z, b1.z), f7 = phi_f(a1.w, s1.w, b1.w);
            float ds = f0*z0.x + f1*z0.y + f2*z0.z + f3*z0.w
                     + f4*z1.x + f5*z1.y + f6*z1.z + f7*z1.w;
            if (tl == 0) dden0 += ds; else dden1 += ds;
            uint4 uu = { pack2(f0,f1), pack2(f2,f3), pack2(f4,f5), pack2(f6,f7) };
            pq[tl][ks] = __builtin_bit_cast(bf16x8, uu);
        }
    }
    s0_write(0);
    bar_lgkm();   // B0: sbL + S0 quarter-0 visible

    f32x4 acc[2][8];
    #pragma unroll
    for (int tl = 0; tl < 2; ++tl)
        #pragma unroll
        for (int et = 0; et < 8; ++et) acc[tl][et] = (f32x4){0.f,0.f,0.f,0.f};

    auto term1q = [&](int qt, int qb) {
        const uint32_t swz = (uint32_t)((i15 & 7) << 4);
        #pragma unroll
        for (int ks = 0; ks < 4; ++ks)
            #pragma unroll
            for (int etl = 0; etl < 2; ++etl) {
                const int et = 2*qt + etl;
                bf16x8 sb = *(const bf16x8*)(S0q + qb*8192 +
                    (((uint32_t)((16*etl+i15)*256 + (32*ks + 8*q4)*2)) ^ swz));
                acc[0][et] = __builtin_amdgcn_mfma_f32_16x16x32_bf16(pq[0][ks], sb, acc[0][et], 0, 0, 0);
                acc[1][et] = __builtin_amdgcn_mfma_f32_16x16x32_bf16(pq[1][ks], sb, acc[1][et], 0, 0, 0);
            }
    };

    // I0
    s0_load(1);
    stage_kv(0);
    load_kv(1);
    term1q(0, 0);
    s0_write(1);
    bar_lgkm();   // B1
    // I1
    s0_load(2);
    stage_kv(1);
    load_kv(2);
    term1q(1, 1);
    s0_write(2);  // -> buf0 (q0 reads finished at B1)
    bar_lgkm();   // B2
    // I2
    s0_load(3);
    term1q(2, 0);
    s0_write(3);  // -> buf1 (q1 reads finished at B2)
    bar_lgkm();   // B3
    // I3
    term1q(3, 1);
    bar_lgkm();   // B4: S0q dead -> Ascr; bufs g0,g1 staged; g2 in regs

    // ---- kv loop: 8 granules of 32 rows, double-buffered
    char* Ascr = smem + wid*1280;         // wave-private [16 q][40 r] bf16
    const uint32_t swzf = (uint32_t)((i15 & 7) << 4);

    for (int t = 0; t < 8; ++t) {
        if (t >= 1) {
            if (t + 1 <= 7) stage_kv((t+1)&1);
            if (t + 2 <= 7) load_kv(t+2);
        }
        const char* pk = pkB + (t&1)*8192;
        const char* vt = vtB + (t&1)*10240;
        #pragma unroll
        for (int tl = 0; tl < 2; ++tl) {
            const int jm = tl ? jm1 : jm0;
            if (t <= jm) {
                f32x4 Aacc[2];
                Aacc[0] = (f32x4){0.f,0.f,0.f,0.f};
                Aacc[1] = (f32x4){0.f,0.f,0.f,0.f};
                #pragma unroll
                for (int ks = 0; ks < 4; ++ks) {
                    bf16x8 ak0 = *(const bf16x8*)(pk + (((uint32_t)((     i15)*256 + (32*ks + 8*q4)*2)) ^ swzf));
                    bf16x8 ak1 = *(const bf16x8*)(pk + (((uint32_t)((16 + i15)*256 + (32*ks + 8*q4)*2)) ^ swzf));
                    bf16x8 pqv = tl ? pq[1][ks] : pq[0][ks];
                    Aacc[0] = __builtin_amdgcn_mfma_f32_16x16x32_bf16(ak0, pqv, Aacc[0], 0, 0, 0);
                    Aacc[1] = __builtin_amdgcn_mfma_f32_16x16x32_bf16(ak1, pqv, Aacc[1], 0, 0, 0);
                }
                float dsum = Aacc[0][0]+Aacc[0][1]+Aacc[0][2]+Aacc[0][3]
                           + Aacc[1][0]+Aacc[1][1]+Aacc[1][2]+Aacc[1][3];
                if (tl == 0) dden0 += dsum; else dden1 += dsum;
                #pragma unroll
                for (int sub = 0; sub < 2; ++sub) {
                    uint2 o;
                    o.x = pack2(Aacc[sub][0], Aacc[sub][1]);
                    o.y = pack2(Aacc[sub][2], Aacc[sub][3]);
                    *(uint2*)(Ascr + (uint32_t)((i15*40 + 16*sub + 4*q4)*2)) = o;
                }
                bf16x8 aq = *(const bf16x8*)(Ascr + (uint32_t)((i15*40 + 8*q4)*2));
                #pragma unroll
                for (int et = 0; et < 8; ++et) {
                    bf16x8 bv = *(const bf16x8*)(vt + (uint32_t)((16*et+i15)*80 + q4*16));
                    acc[tl][et] = __builtin_amdgcn_mfma_f32_16x16x32_bf16(aq, bv, acc[tl][et], 0, 0, 0);
                }
            }
        }
        bar_lgkm();
    }

    // ---- den reduce + normalize + store
    dden0 += __shfl_xor(dden0, 16, 64); dden0 += __shfl_xor(dden0, 32, 64);
    dden1 += __shfl_xor(dden1, 16, 64); dden1 += __shfl_xor(dden1, 32, 64);
    if (q4 == 0) {
        denl[wid*32 + i15]      = dden0;
        denl[wid*32 + 16 + i15] = dden1;
    }
    #pragma unroll
    for (int tl = 0; tl < 2; ++tl) {
        const int a = tl ? qa1 : qa0;
        float inv[4];
        #pragma unroll
        for (int r = 0; r < 4; ++r)
            inv[r] = 1.0f / fmaxf(denl[wid*32 + 16*tl + 4*q4 + r], 1e-6f);
        #pragma unroll
        for (int et = 0; et < 8; ++et)
            #pragma unroll
            for (int r = 0; r < 4; ++r)
                out[base + (size_t)(row0 + 16*a + 4*q4 + r)*DDIM + 16*et + i15] =
                    acc[tl][et][r] * inv[r];
    }
}

extern "C" void kernel_launch(void* const* d_in, const int* in_sizes, int n_in,
                              void* d_out, int out_size, void* d_ws, size_t ws_size,
                              hipStream_t stream) {
    const float* Q     = (const float*)d_in[0];
    const float* K     = (const float*)d_in[1];
    const float* V     = (const float*)d_in[2];
    const float* scale = (const float*)d_in[3];
    const float* bias  = (const float*)d_in[4];
    float* out    = (float*)d_out;
    float* states = (float*)d_ws;   // 32*16*16512*4 = 33.8 MB

    hipLaunchKernelGGL(la_state, dim3(BH*CHUNKS), dim3(512), SMEM1, stream,
                       K, V, scale, bias, states);
    hipLaunchKernelGGL(la_prefix, dim3(33, BH), dim3(128), 0, stream, states);
    hipLaunchKernelGGL(la_fwd, dim3(BH*CHUNKS), dim3(512), SMEM2, stream,
                       Q, K, V, scale, bias, states, out);
}

// Round 8
// 276.954 us; speedup vs baseline: 1.0503x; 1.0062x over previous
//
#include <hip/hip_runtime.h>
#include <stdint.h>

#define BH 32
#define LSEQ 4096
#define DDIM 128
#define CHUNKS 16
#define CHUNK_ROWS 256
#define STATE_SZ (DDIM*DDIM + DDIM)   // 16512 floats per (bh, chunk), [d][e] then Z[d]

typedef __attribute__((ext_vector_type(8))) short bf16x8;
typedef __attribute__((ext_vector_type(4))) float f32x4;

__device__ inline uint16_t f2bf(float f) {
    uint32_t x = __builtin_bit_cast(uint32_t, f);
    x += 0x7fffu + ((x >> 16) & 1u);
    return (uint16_t)(x >> 16);
}
__device__ inline uint32_t pack2(float a, float b) {
    return (uint32_t)f2bf(a) | ((uint32_t)f2bf(b) << 16);
}
// phi(x) = clip(elu(x*s+b)+1, 0, 10)
__device__ inline float phi_f(float x, float s, float b) {
    float y = fmaf(x, s, b);
    float pos = fminf(y + 1.0f, 10.0f);
    float neg = __expf(y);
    return (y > 0.0f) ? pos : neg;
}
// LDS-only barrier drain: keeps global prefetch loads in flight across barriers.
__device__ inline void bar_lgkm() {
    asm volatile("s_waitcnt lgkmcnt(0)\n\ts_barrier" ::: "memory");
}

// =====================================================================
// P1: per-chunk state totals  S_c = phi_K_c^T @ V_c  (K=256), Z_c
// 32-row granules, double-buffered. LDS 34816 B.
// (512,4) forces arch VGPR cap 64 -> with AGPR block (32) total 128/wave
// -> 4 waves/SIMD -> 2 wg/CU (register-quantum model, R7 post-mortem).
#define SMEM1 34816
__global__ __launch_bounds__(512, 4) void la_state(
    const float* __restrict__ K, const float* __restrict__ V,
    const float* __restrict__ scale, const float* __restrict__ bias,
    float* __restrict__ states)
{
    extern __shared__ char smem[];
    const int tid  = threadIdx.x;
    const int bh   = blockIdx.x >> 4;
    const int ch   = blockIdx.x & 15;
    const int h    = bh & 15;
    const int lane = tid & 63;
    const int wid  = tid >> 6;
    const int i15  = lane & 15;
    const int q4   = lane >> 4;
    const size_t base = (size_t)bh * LSEQ * DDIM;
    const int row0 = ch * CHUNK_ROWS;

    const int d  = tid & 127;
    const int rg = tid >> 7;              // 0..3 -> rows 8rg..8rg+7 of a 32-row granule
    const float sk = scale[h*DDIM + d];
    const float bk = bias [h*DDIM + d];

    f32x4 accS[8];
    #pragma unroll
    for (int mt = 0; mt < 8; ++mt) accS[mt] = (f32x4){0.f,0.f,0.f,0.f};
    float zacc = 0.f;

    float kreg[8], vreg[8];
    auto load_kv = [&](int g) {
        const float* Kc = K + base + (size_t)(row0 + 32*g + 8*rg)*DDIM + d;
        const float* Vc = V + base + (size_t)(row0 + 32*g + 8*rg)*DDIM + d;
        #pragma unroll
        for (int j = 0; j < 8; ++j) {
            kreg[j] = Kc[(size_t)j*DDIM];
            vreg[j] = Vc[(size_t)j*DDIM];
        }
    };
    auto stage = [&](int b) {   // current regs -> buf b, transposed [col][r]
        uint32_t wk[4], wv[4];
        #pragma unroll
        for (int j = 0; j < 4; ++j) {
            float p0 = phi_f(kreg[2*j],   sk, bk);
            float p1 = phi_f(kreg[2*j+1], sk, bk);
            zacc += p0 + p1;
            wk[j] = pack2(p0, p1);
            wv[j] = pack2(vreg[2*j], vreg[2*j+1]);
        }
        const uint32_t off = ((uint32_t)(d*64 + rg*16)) ^ ((uint32_t)((d&7)<<4));
        *(uint4*)(smem + b*8192 + off)         = *(const uint4*)wk;
        *(uint4*)(smem + 16384 + b*8192 + off) = *(const uint4*)wv;
    };

    load_kv(0);
    stage(0);
    load_kv(1);
    bar_lgkm();

    for (int g = 0; g < 8; ++g) {
        if (g + 1 < 8) stage((g+1)&1);
        if (g + 2 < 8) load_kv(g+2);
        const char* pkb = smem + (g&1)*8192;
        const char* vtb = smem + 16384 + (g&1)*8192;
        const uint32_t swz = (uint32_t)((i15&7)<<4);
        bf16x8 bv = *(const bf16x8*)(vtb + (((uint32_t)((16*wid+i15)*64 + q4*16)) ^ swz));
        #pragma unroll
        for (int mt = 0; mt < 8; ++mt) {
            bf16x8 av = *(const bf16x8*)(pkb + (((uint32_t)((16*mt+i15)*64 + q4*16)) ^ swz));
            accS[mt] = __builtin_amdgcn_mfma_f32_16x16x32_bf16(av, bv, accS[mt], 0, 0, 0);
        }
        bar_lgkm();
    }

    float* Zpart = (float*)(smem + 32768);
    Zpart[rg*128 + d] = zacc;
    float* stb = states + (size_t)(bh*CHUNKS + ch)*STATE_SZ;
    #pragma unroll
    for (int mt = 0; mt < 8; ++mt)
        #pragma unroll
        for (int r = 0; r < 4; ++r)
            stb[(size_t)(16*mt + 4*q4 + r)*DDIM + 16*wid + i15] = accS[mt][r];
    bar_lgkm();
    if (tid < 128)
        stb[DDIM*DDIM + tid] = Zpart[tid] + Zpart[128+tid] + Zpart[256+tid] + Zpart[384+tid];
}

// =====================================================================
// Prefix: in-place exclusive prefix over the 16 chunk states, float4 chains.
__global__ void la_prefix(float* __restrict__ states) {
    const int bh  = blockIdx.y;
    const int idx = blockIdx.x * 128 + threadIdx.x;
    if (idx >= STATE_SZ/4) return;            // 4128 float4 chains per bh
    float4* p = (float4*)(states + (size_t)bh * CHUNKS * STATE_SZ) + idx;
    float4 run = {0.f, 0.f, 0.f, 0.f};
    #pragma unroll
    for (int c = 0; c < CHUNKS; ++c) {
        float4 v = p[(size_t)c * (STATE_SZ/4)];
        p[(size_t)c * (STATE_SZ/4)] = run;
        run.x += v.x; run.y += v.y; run.z += v.z; run.w += v.w;
    }
}

// =====================================================================
// P2: out = (phi_Q @ S0 + blockcausal(phi_Q @ phi_K^T) @ V) / den
// HALF-CHUNK per wg (128 q-rows), wave w owns one 16-row q-tile
// (a = 8*half + w). Arch regs forced to 64 via (512,4); acc (32) + Aacc (8)
// live in the AGPR block (<=64) -> total 128/wave -> 2 wg/CU.
// Grid 1024, XCD-contiguous bijective remap (both halves of a chunk share
// K/V granules + S0 through the same XCD L2).
// LDS map (71168 B):
//   [0,32768)       S0T [e=128][d=128] bf16 swz (e&7)<<4; after B1 ->
//                   Ascr per wave (wid*1280, [16 q][40 r] bf16)
//   [32768,49152)   pk bufs 2 x [32 r][128 d] bf16 swz (8KB each)
//   [49152,69632)   vT bufs 2 x [128 e][40 r] bf16 pad (10KB each)
//   [69632,70656)   sbL: scale[128], bias[128] f32
//   [70656,71168)   denl [8 waves][16] f32
#define SMEM2 71168
__global__ __launch_bounds__(512, 4) void la_fwd(
    const float* __restrict__ Q, const float* __restrict__ K,
    const float* __restrict__ V, const float* __restrict__ scale,
    const float* __restrict__ bias, const float* __restrict__ states,
    float* __restrict__ out)
{
    extern __shared__ char smem[];
    char* S0T  = smem;
    char* pkB  = smem + 32768;
    char* vtB  = smem + 49152;
    float* sbL  = (float*)(smem + 69632);
    float* denl = (float*)(smem + 70656);

    const int tid  = threadIdx.x;
    const int b    = blockIdx.x;
    const int lid  = ((b & 7) << 7) | (b >> 3);   // bijective, 1024 = 8*128
    const int half = lid & 1;
    const int cgid = lid >> 1;
    const int bh   = cgid >> 4;
    const int ch   = cgid & 15;
    const int h    = bh & 15;
    const int lane = tid & 63;
    const int wid  = tid >> 6;
    const int i15  = lane & 15;
    const int q4   = lane >> 4;
    const size_t base = (size_t)bh * LSEQ * DDIM;
    const int row0  = ch * CHUNK_ROWS;
    const int qrow0 = row0 + half*128;
    const int NG    = 4 + 4*half;          // kv granules (32 rows) needed
    const int jm    = 4*half + (wid >> 1); // last granule for this wave's tile
    const float* stb = states + (size_t)(bh*CHUNKS + ch)*STATE_SZ;

    // kv staging (32-row granule)
    const int krow = tid >> 4;            // 0..31
    const int kc8  = (tid & 15) * 8;      // K col segment
    const int ve   = tid & 127;           // vT row (e)
    const int vrg  = tid >> 7;            // r rows 8vrg..8vrg+7
    // S0 staging
    const int se  = tid & 127;            // e
    const int sdg = tid >> 7;             // d block 32sdg..32sdg+31

    float4 kq[2];
    float  vr[8];
    auto load_kv = [&](int g) {
        const float* Kr = K + base + (size_t)(row0 + 32*g + krow)*DDIM + kc8;
        kq[0] = *(const float4*)(Kr);
        kq[1] = *(const float4*)(Kr + 4);
        const float* Vc = V + base + (size_t)(row0 + 32*g + 8*vrg)*DDIM + ve;
        #pragma unroll
        for (int j = 0; j < 8; ++j) vr[j] = Vc[(size_t)j*DDIM];
    };
    auto stage_kv = [&](int bb) {   // reads sbL -> only call after B0
        float4 s0 = *(const float4*)&sbL[kc8];
        float4 s1 = *(const float4*)&sbL[kc8 + 4];
        float4 b0 = *(const float4*)&sbL[128 + kc8];
        float4 b1 = *(const float4*)&sbL[128 + kc8 + 4];
        uint32_t wk[4];
        wk[0] = pack2(phi_f(kq[0].x, s0.x, b0.x), phi_f(kq[0].y, s0.y, b0.y));
        wk[1] = pack2(phi_f(kq[0].z, s0.z, b0.z), phi_f(kq[0].w, s0.w, b0.w));
        wk[2] = pack2(phi_f(kq[1].x, s1.x, b1.x), phi_f(kq[1].y, s1.y, b1.y));
        wk[3] = pack2(phi_f(kq[1].z, s1.z, b1.z), phi_f(kq[1].w, s1.w, b1.w));
        const uint32_t lin = (uint32_t)(krow*256 + kc8*2);
        const uint32_t swz = (uint32_t)((krow & 7) << 4);
        *(uint4*)(pkB + bb*8192 + (lin ^ swz)) = *(const uint4*)wk;
        uint32_t wv[4];
        #pragma unroll
        for (int j = 0; j < 4; ++j) wv[j] = pack2(vr[2*j], vr[2*j+1]);
        *(uint4*)(vtB + bb*10240 + (uint32_t)(ve*80 + vrg*16)) = *(const uint4*)wv;
    };

    load_kv(0);   // in flight through the whole prologue
    if (tid < 256) sbL[tid] = (tid < 128) ? scale[h*DDIM + tid] : bias[h*DDIM + tid - 128];

    // ---- stage S0T [e][d] bf16, 4 low-pressure passes of 8 d's each
    {
        const uint32_t swz = (uint32_t)((se & 7) << 4);
        #pragma unroll
        for (int p = 0; p < 4; ++p) {
            const int d0 = 32*sdg + 8*p;
            float sv[8];
            const float* sp = stb + (size_t)d0*DDIM + se;
            #pragma unroll
            for (int j = 0; j < 8; ++j) sv[j] = sp[(size_t)j*DDIM];
            uint32_t w[4];
            #pragma unroll
            for (int j = 0; j < 4; ++j) w[j] = pack2(sv[2*j], sv[2*j+1]);
            *(uint4*)(S0T + (((uint32_t)(se*256 + d0*2)) ^ swz)) = *(const uint4*)w;
        }
    }

    // ---- phi_Q fragment (single tile) + den0 = phi_q . Z0
    bf16x8 pq[4];
    float dden = 0.f;
    #pragma unroll
    for (int ks = 0; ks < 4; ++ks) {
        const float* sp = scale + h*DDIM + 32*ks + 8*q4;
        const float* bp = bias  + h*DDIM + 32*ks + 8*q4;
        const float* zp = stb + DDIM*DDIM + 32*ks + 8*q4;
        float4 s0 = *(const float4*)sp, s1 = *(const float4*)(sp+4);
        float4 b0 = *(const float4*)bp, b1 = *(const float4*)(bp+4);
        float4 z0 = *(const float4*)zp, z1 = *(const float4*)(zp+4);
        const float* qp = Q + base + (size_t)(qrow0 + 16*wid + i15)*DDIM + 32*ks + 8*q4;
        float4 a0 = *(const float4*)qp, a1 = *(const float4*)(qp+4);
        float f0 = phi_f(a0.x, s0.x, b0.x), f1 = phi_f(a0.y, s0.y, b0.y);
        float f2 = phi_f(a0.z, s0.z, b0.z), f3 = phi_f(a0.w, s0.w, b0.w);
        float f4 = phi_f(a1.x, s1.x, b1.x), f5 = phi_f(a1.y, s1.y, b1.y);
        float f6 = phi_f(a1.z, s1.z, b1.z), f7 = phi_f(a1.w, s1.w, b1.w);
        dden += f0*z0.x + f1*z0.y + f2*z0.z + f3*z0.w
              + f4*z1.x + f5*z1.y + f6*z1.z + f7*z1.w;
        uint4 uu = { pack2(f0,f1), pack2(f2,f3), pack2(f4,f5), pack2(f6,f7) };
        pq[ks] = __builtin_bit_cast(bf16x8, uu);
    }

    bar_lgkm();   // B0: sbL + S0T visible
    stage_kv(0);  // g0 regs -> buf0 (reads sbL, safely after B0)
    load_kv(1);

    // ---- term1: acc = phi_q @ S0
    f32x4 acc[8];
    #pragma unroll
    for (int et = 0; et < 8; ++et) acc[et] = (f32x4){0.f,0.f,0.f,0.f};
    {
        const uint32_t swz = (uint32_t)((i15 & 7) << 4);
        #pragma unroll
        for (int ks = 0; ks < 4; ++ks)
            #pragma unroll
            for (int et = 0; et < 8; ++et) {
                bf16x8 sb = *(const bf16x8*)(S0T + (((uint32_t)((16*et+i15)*256 + (32*ks + 8*q4)*2)) ^ swz));
                acc[et] = __builtin_amdgcn_mfma_f32_16x16x32_bf16(pq[ks], sb, acc[et], 0, 0, 0);
            }
    }
    stage_kv(1);
    load_kv(2);
    bar_lgkm();   // B1: term1 S0T reads done -> Ascr may overwrite; bufs g0,g1 visible

    // ---- kv loop: NG granules of 32 rows, double-buffered
    char* Ascr = S0T + wid*1280;          // wave-private [16 q][40 r] bf16
    const uint32_t swzf = (uint32_t)((i15 & 7) << 4);

    for (int t = 0; t < NG; ++t) {
        if (t >= 1) {
            if (t + 1 < NG) stage_kv((t+1)&1);
            if (t + 2 < NG) load_kv(t+2);
        }
        const char* pk = pkB + (t&1)*8192;
        const char* vt = vtB + (t&1)*10240;
        if (t <= jm) {
            f32x4 Aacc[2];
            Aacc[0] = (f32x4){0.f,0.f,0.f,0.f};
            Aacc[1] = (f32x4){0.f,0.f,0.f,0.f};
            #pragma unroll
            for (int ks = 0; ks < 4; ++ks) {
                bf16x8 ak0 = *(const bf16x8*)(pk + (((uint32_t)((     i15)*256 + (32*ks + 8*q4)*2)) ^ swzf));
                bf16x8 ak1 = *(const bf16x8*)(pk + (((uint32_t)((16 + i15)*256 + (32*ks + 8*q4)*2)) ^ swzf));
                Aacc[0] = __builtin_amdgcn_mfma_f32_16x16x32_bf16(ak0, pq[ks], Aacc[0], 0, 0, 0);
                Aacc[1] = __builtin_amdgcn_mfma_f32_16x16x32_bf16(ak1, pq[ks], Aacc[1], 0, 0, 0);
            }
            dden += Aacc[0][0]+Aacc[0][1]+Aacc[0][2]+Aacc[0][3]
                  + Aacc[1][0]+Aacc[1][1]+Aacc[1][2]+Aacc[1][3];
            #pragma unroll
            for (int sub = 0; sub < 2; ++sub) {
                uint2 o;
                o.x = pack2(Aacc[sub][0], Aacc[sub][1]);
                o.y = pack2(Aacc[sub][2], Aacc[sub][3]);
                *(uint2*)(Ascr + (uint32_t)((i15*40 + 16*sub + 4*q4)*2)) = o;
            }
            bf16x8 aq = *(const bf16x8*)(Ascr + (uint32_t)((i15*40 + 8*q4)*2));
            #pragma unroll
            for (int et = 0; et < 8; ++et) {
                bf16x8 bv = *(const bf16x8*)(vt + (uint32_t)((16*et+i15)*80 + q4*16));
                acc[et] = __builtin_amdgcn_mfma_f32_16x16x32_bf16(aq, bv, acc[et], 0, 0, 0);
            }
        }
        bar_lgkm();
    }

    // ---- den reduce (wave-private) + normalize + store
    dden += __shfl_xor(dden, 16, 64);
    dden += __shfl_xor(dden, 32, 64);
    if (q4 == 0) denl[wid*16 + i15] = dden;
    float inv[4];
    #pragma unroll
    for (int r = 0; r < 4; ++r)
        inv[r] = 1.0f / fmaxf(denl[wid*16 + 4*q4 + r], 1e-6f);
    #pragma unroll
    for (int et = 0; et < 8; ++et)
        #pragma unroll
        for (int r = 0; r < 4; ++r)
            out[base + (size_t)(qrow0 + 16*wid + 4*q4 + r)*DDIM + 16*et + i15] =
                acc[et][r] * inv[r];
}

extern "C" void kernel_launch(void* const* d_in, const int* in_sizes, int n_in,
                              void* d_out, int out_size, void* d_ws, size_t ws_size,
                              hipStream_t stream) {
    const float* Q     = (const float*)d_in[0];
    const float* K     = (const float*)d_in[1];
    const float* V     = (const float*)d_in[2];
    const float* scale = (const float*)d_in[3];
    const float* bias  = (const float*)d_in[4];
    float* out    = (float*)d_out;
    float* states = (float*)d_ws;   // 32*16*16512*4 = 33.8 MB

    static bool s_attr = false;
    if (!s_attr) {
        hipFuncSetAttribute(reinterpret_cast<const void*>(la_fwd),
                            hipFuncAttributeMaxDynamicSharedMemorySize, SMEM2);
        s_attr = true;
    }

    hipLaunchKernelGGL(la_state, dim3(BH*CHUNKS), dim3(512), SMEM1, stream,
                       K, V, scale, bias, states);
    hipLaunchKernelGGL(la_prefix, dim3(33, BH), dim3(128), 0, stream, states);
    hipLaunchKernelGGL(la_fwd, dim3(BH*CHUNKS*2), dim3(512), SMEM2, stream,
                       Q, K, V, scale, bias, states, out);
}